// Round 6
// baseline (93.705 us; speedup 1.0000x reference)
//
#include <hip/hip_runtime.h>

// n-step return: T=1024, B=4096, gamma=0.99, horizon=16, fp32 in/out.
// G[t,b] = sum_{h=0}^{15} g^h * rm[t+h,b]  (rm = rewards*masks, zero-padded)
//        + g^{min(t+16,T)-t} * values[min(t+15,T-1), b]
//
// R5 post-mortem: all VGPR-staged designs stuck at ~32-38us kernel; suspect
// spills + VGPR-coupled MLP. R6: async global_load_lds (width=16) staging --
// bytes in flight decoupled from VGPR (m93->m97 lesson). Block = 64 cols x
// 32 out-rows; LDS holds rewards[48 rows] + masks[48 rows] + pre-clamped
// values[32 rows] = 32KB -> 5 blocks/CU, 20 waves/CU, 2048 blocks. DMA is
// issued as 1KB granules (4 rows x 64 cols): wave-uniform LDS base, HW writes
// lane*16B, global addr = lane-matched (row 4g+l/16, col (l%16)*4). Compute
// phase is pure LDS, all-lane-same-row => 2-way bank alias = free.

constexpr int   T_DIM    = 1024;
constexpr int   B_DIM    = 4096;
constexpr int   H        = 16;
constexpr int   COLS     = 64;
constexpr int   ROWS_OUT = 32;
constexpr int   ROWS_LDS = 48;            // 47 needed (32+15), padded to 4-row granule
constexpr int   BLOCK    = 256;           // 4 waves
constexpr float GAMMA    = 0.99f;

constexpr float gpow_c(int n) {
    float g = 1.0f;
    for (int i = 0; i < n; ++i) g *= GAMMA;
    return g;
}
constexpr float G16 = gpow_c(16);

constexpr int NG_RM = ROWS_LDS / 4;       // 12 granules for rewards, 12 for masks
constexpr int NG_V  = ROWS_OUT / 4;       // 8 granules for values
constexpr int NG    = 2 * NG_RM + NG_V;   // 32 total

__device__ __forceinline__ void async_g2l16(const float* gp, float* lds_base) {
    __builtin_amdgcn_global_load_lds(
        (const __attribute__((address_space(1))) void*)gp,
        (__attribute__((address_space(3))) void*)lds_base, 16, 0, 0);
}

__global__ __launch_bounds__(BLOCK)
void NStepReturn_88691074662796_kernel(const float* __restrict__ rewards,
                                       const float* __restrict__ values,
                                       const float* __restrict__ masks,
                                       float* __restrict__ out)
{
    __shared__ float lds_r[ROWS_LDS * COLS];   // 12288 B
    __shared__ float lds_m[ROWS_LDS * COLS];   // 12288 B
    __shared__ float lds_v[ROWS_OUT * COLS];   //  8192 B   total 32768 B

    const int tid  = threadIdx.x;
    const int c0   = blockIdx.x * COLS;
    const int t0   = blockIdx.y * ROWS_OUT;
    const int w    = tid >> 6;                 // wave 0..3
    const int lane = tid & 63;
    const int rowsub = lane >> 4;              // 0..3 (row within granule)
    const int colsub = (lane & 15) * 4;        // 0,4,..,60 (col within tile)

    // ---- async DMA staging: 32 x 1KB granules round-robined over 4 waves ----
    for (int g = w; g < NG; g += 4) {
        if (g < NG_RM) {                       // rewards granule
            const int gi = g;
            if (t0 + 4 * gi < T_DIM) {         // uniform per granule (clean 4-row split)
                const int t = t0 + 4 * gi + rowsub;
                async_g2l16(rewards + (size_t)t * B_DIM + (c0 + colsub), &lds_r[gi * 256]);
            } else {                           // past T: zero-pad (last t-chunk only)
                *(float4*)&lds_r[gi * 256 + lane * 4] = make_float4(0.f, 0.f, 0.f, 0.f);
            }
        } else if (g < 2 * NG_RM) {            // masks granule
            const int gi = g - NG_RM;
            if (t0 + 4 * gi < T_DIM) {
                const int t = t0 + 4 * gi + rowsub;
                async_g2l16(masks + (size_t)t * B_DIM + (c0 + colsub), &lds_m[gi * 256]);
            } else {
                *(float4*)&lds_m[gi * 256 + lane * 4] = make_float4(0.f, 0.f, 0.f, 0.f);
            }
        } else {                               // values granule (pre-clamped row index)
            const int gi  = g - 2 * NG_RM;
            const int row = 4 * gi + rowsub;
            const int tv  = min(t0 + H - 1 + row, T_DIM - 1);
            async_g2l16(values + (size_t)tv * B_DIM + (c0 + colsub), &lds_v[gi * 256]);
        }
    }
    __syncthreads();                           // drains vmcnt (incl. global_load_lds)

    // ---- sliding-window recurrence from LDS: thread = (col, 8-row strip) ----
    const int c  = lane;                       // column within tile
    const int r0 = w * 8;                      // rows r0..r0+7; taps reach r0+22 < 48

    // init: W(r0+7) = sum_{h=0}^{15} g^h rm[r0+7+h]  (Horner)
    float W = 0.0f;
    #pragma unroll
    for (int h = H - 1; h >= 0; --h) {
        const int row = r0 + 7 + h;
        W = lds_r[row * COLS + c] * lds_m[row * COLS + c] + GAMMA * W;
    }

    {   // store strip's last row
        const int t = t0 + r0 + 7;
        float gb = G16;
        if (t + H > T_DIM) {                   // wave-uniform; last chunk only
            gb = 1.0f;
            for (int k = 0; k < T_DIM - t; ++k) gb *= GAMMA;
        }
        out[(size_t)t * B_DIM + c0 + c] = W + gb * lds_v[(r0 + 7) * COLS + c];
    }

    // backward: W(t) = rm[t] + g*W(t+1) - g^16*rm[t+16]
    #pragma unroll
    for (int j = 6; j >= 0; --j) {
        const int rj = r0 + j;
        W = lds_r[rj * COLS + c] * lds_m[rj * COLS + c] + GAMMA * W
          - G16 * lds_r[(rj + H) * COLS + c] * lds_m[(rj + H) * COLS + c];

        const int t = t0 + rj;
        float gb = G16;
        if (t + H > T_DIM) {
            gb = 1.0f;
            for (int k = 0; k < T_DIM - t; ++k) gb *= GAMMA;
        }
        out[(size_t)t * B_DIM + c0 + c] = W + gb * lds_v[rj * COLS + c];
    }
}

extern "C" void kernel_launch(void* const* d_in, const int* in_sizes, int n_in,
                              void* d_out, int out_size, void* d_ws, size_t ws_size,
                              hipStream_t stream) {
    const float* rewards = (const float*)d_in[0];
    const float* values  = (const float*)d_in[1];
    const float* masks   = (const float*)d_in[2];
    float* out = (float*)d_out;

    dim3 grid(B_DIM / COLS, T_DIM / ROWS_OUT);   // (64, 32) = 2048 blocks
    dim3 block(BLOCK);
    NStepReturn_88691074662796_kernel<<<grid, block, 0, stream>>>(rewards, values, masks, out);
}